// Round 6
// baseline (670.249 us; speedup 1.0000x reference)
//
#include <hip/hip_runtime.h>

#define DD 128
#define NBC 64  // CSR edge chunks

// ---------------- CSR build (atomic-free at global scope) ----------------

// 128 blocks: blocks [0,64) build per-chunk dst histograms, [64,128) src.
// Packed 2-nodes-per-word LDS histogram (low/high uint16 fields); per-field
// count <= chunk size (12.5K) so no carry between fields.
__global__ __launch_bounds__(256) void hist2_kernel(const int* __restrict__ src,
                                                    const int* __restrict__ dst,
                                                    unsigned int* __restrict__ hsrc,
                                                    unsigned int* __restrict__ hdst,
                                                    int e, int n, int ec) {
  __shared__ unsigned int h[32768];  // 128 KB: supports n <= 65536
  int c = blockIdx.x & (NBC - 1);
  bool is_src = blockIdx.x >= NBC;
  const int* __restrict__ ids = is_src ? src : dst;
  unsigned int* __restrict__ out = is_src ? hsrc : hdst;
  int nw = (n + 1) >> 1;
  for (int w = threadIdx.x; w < nw; w += 256) h[w] = 0u;
  __syncthreads();
  int lo = c * ec;
  int hi = lo + ec; if (hi > e) hi = e;
  for (int i = lo + threadIdx.x; i < hi; i += 256) {
    int d = ids[i];
    atomicAdd(&h[d >> 1], (d & 1) ? 0x10000u : 1u);
  }
  __syncthreads();
  for (int w = threadIdx.x; w < nw; w += 256) out[(size_t)c * nw + w] = h[w];
}

// Reduce private hists -> degrees, norms; deg_in (int) feeds the scan.
__global__ __launch_bounds__(256) void degnorm_kernel(const unsigned int* __restrict__ hsrc,
                                                      const unsigned int* __restrict__ hdst,
                                                      int* __restrict__ deg_in,
                                                      float* __restrict__ norm_src,
                                                      float* __restrict__ norm_dst, int n) {
  int nw = (n + 1) >> 1;
  int w = blockIdx.x * 256 + threadIdx.x;
  if (w >= nw) return;
  unsigned int slo = 0, shi = 0, dlo = 0, dhi = 0;
  for (int c = 0; c < NBC; ++c) {
    unsigned int a = hsrc[(size_t)c * nw + w];
    unsigned int b = hdst[(size_t)c * nw + w];
    slo += a & 0xFFFFu; shi += a >> 16;
    dlo += b & 0xFFFFu; dhi += b >> 16;
  }
  int n0 = 2 * w, n1 = 2 * w + 1;
  deg_in[n0] = (int)dlo;
  norm_src[n0] = 1.0f / sqrtf((float)(slo < 1u ? 1u : slo));
  norm_dst[n0] = 1.0f / sqrtf((float)(dlo < 1u ? 1u : dlo));
  if (n1 < n) {
    deg_in[n1] = (int)dhi;
    norm_src[n1] = 1.0f / sqrtf((float)(shi < 1u ? 1u : shi));
    norm_dst[n1] = 1.0f / sqrtf((float)(dhi < 1u ? 1u : dhi));
  }
}

// Multi-block scan, phase 1: per-block (2048-elem) sums.
__global__ __launch_bounds__(256) void scan_partial_kernel(const int* __restrict__ cnt,
                                                           int* __restrict__ bsum, int n) {
  __shared__ int ws[4];
  int tid = threadIdx.x;
  int base = blockIdx.x * 2048 + tid * 8;
  int s = 0;
#pragma unroll
  for (int i = 0; i < 8; ++i) {
    int id = base + i;
    if (id < n) s += cnt[id];
  }
#pragma unroll
  for (int d = 32; d; d >>= 1) s += __shfl_xor(s, d, 64);
  int lane = tid & 63, wid = tid >> 6;
  if (lane == 0) ws[wid] = s;
  __syncthreads();
  if (tid == 0) bsum[blockIdx.x] = ws[0] + ws[1] + ws[2] + ws[3];
}

// Phase 2: exclusive scan of block sums (single wave).
__global__ __launch_bounds__(64) void scan_bsum_kernel(int* __restrict__ bsum, int nb) {
  int lane = threadIdx.x;
  int run = 0;
  for (int base = 0; base < nb; base += 64) {
    int id = base + lane;
    int v = (id < nb) ? bsum[id] : 0;
    int sc = v;
#pragma unroll
    for (int d = 1; d < 64; d <<= 1) {
      int t = __shfl_up(sc, d, 64);
      if (lane >= d) sc += t;
    }
    if (id < nb) bsum[id] = run + sc - v;
    run += __shfl(sc, 63, 64);
  }
}

// Phase 3: scatter exclusive scan -> row_ptr.
__global__ __launch_bounds__(256) void scan_final_kernel(const int* __restrict__ cnt,
                                                         const int* __restrict__ bsum,
                                                         int* __restrict__ row_ptr,
                                                         int n, int e_total) {
  __shared__ int ws[4];
  int tid = threadIdx.x, lane = tid & 63, wid = tid >> 6;
  int base = blockIdx.x * 2048 + tid * 8;
  int v[8];
  int s = 0;
#pragma unroll
  for (int i = 0; i < 8; ++i) {
    int id = base + i;
    v[i] = (id < n) ? cnt[id] : 0;
    s += v[i];
  }
  int sc = s;
#pragma unroll
  for (int d = 1; d < 64; d <<= 1) {
    int t = __shfl_up(sc, d, 64);
    if (lane >= d) sc += t;
  }
  if (lane == 63) ws[wid] = sc;
  __syncthreads();
  int woff = 0;
  for (int w = 0; w < wid; ++w) woff += ws[w];
  int off = bsum[blockIdx.x] + woff + (sc - s);
#pragma unroll
  for (int i = 0; i < 8; ++i) {
    int id = base + i;
    if (id < n) {
      row_ptr[id] = off;
      off += v[i];
    }
  }
  if (blockIdx.x == 0 && tid == 0) row_ptr[n] = e_total;
}

// In-place: hdst[c][w] <- exclusive prefix over chunks c (packed fields).
__global__ __launch_bounds__(256) void chunkprefix_kernel(unsigned int* __restrict__ hdst,
                                                          int n) {
  int nw = (n + 1) >> 1;
  int w = blockIdx.x * 256 + threadIdx.x;
  if (w >= nw) return;
  unsigned int clo = 0, chi = 0;
  for (int c = 0; c < NBC; ++c) {
    size_t idx = (size_t)c * nw + w;
    unsigned int v = hdst[idx];
    hdst[idx] = clo | (chi << 16);
    clo += v & 0xFFFFu;
    chi += v >> 16;
  }
}

// Fill adj: rank via LDS packed atomic; position = row_ptr[d] + chunk-prefix + rank.
__global__ __launch_bounds__(256) void fillx_kernel(const int* __restrict__ src,
                                                    const int* __restrict__ dst,
                                                    const unsigned int* __restrict__ hdst,
                                                    const int* __restrict__ row_ptr,
                                                    int* __restrict__ adj,
                                                    int e, int n, int ec) {
  __shared__ unsigned int h[32768];
  int c = blockIdx.x;
  int nw = (n + 1) >> 1;
  for (int w = threadIdx.x; w < nw; w += 256) h[w] = 0u;
  __syncthreads();
  int lo = c * ec;
  int hi = lo + ec; if (hi > e) hi = e;
  for (int i = lo + threadIdx.x; i < hi; i += 256) {
    int s = src[i];
    int d = dst[i];
    unsigned int old = atomicAdd(&h[d >> 1], (d & 1) ? 0x10000u : 1u);
    unsigned int rank = (d & 1) ? (old >> 16) : (old & 0xFFFFu);
    unsigned int pre = hdst[(size_t)c * nw + (d >> 1)];
    pre = (d & 1) ? (pre >> 16) : (pre & 0xFFFFu);
    adj[row_ptr[d] + (int)pre + (int)rank] = s;
  }
}

// g[i,:] = feat[i,:] * norm_src[i]
__global__ __launch_bounds__(256) void prescale_kernel(const float* __restrict__ feat,
                                                       const float* __restrict__ ns,
                                                       float* __restrict__ g, int n) {
  int i = blockIdx.x * 256 + threadIdx.x;  // float4 index
  if (i < n * 32) {
    float4 v = ((const float4*)feat)[i];
    float s = ns[i >> 5];
    v.x *= s; v.y *= s; v.z *= s; v.w *= s;
    ((float4*)g)[i] = v;
  }
}

// ---------------- fused layer: agg (gather-sum) + gemm + relu ----------------
// gout[r,:] = relu( (nd[r] * sum_{s in adj[r]} gin[s,:]) @ W + b ) * (last?1:ns[r])
// 32-row tile (16 KB LDS) -> 1563 blocks for occupancy/TLP. Agg: 4 waves x
// 8 nodes, pair-packed float4 gather (lanes 0-31 even edge, 32-63 odd).
// Gemm: 256 thr, thread = 4 rows x 4 cols, W from global (L1/L2-hot).
__global__ __launch_bounds__(256) void layer_kernel(const float* __restrict__ gin,
                                                    float* __restrict__ gout,
                                                    const int* __restrict__ adj,
                                                    const int* __restrict__ row_ptr,
                                                    const float* __restrict__ ns,
                                                    const float* __restrict__ ndv,
                                                    const float* __restrict__ W,
                                                    const float* __restrict__ bias,
                                                    int n, int last) {
  __shared__ float Xs[32][DD];
  int tid = threadIdx.x;
  int lane = tid & 63;
  int wv = tid >> 6;
  int m = lane & 31;
  int half = lane >> 5;
  int row0 = blockIdx.x * 32;
  const float4* g4 = (const float4*)gin;

  for (int r = wv; r < 32; r += 4) {
    int node = row0 + r;
    float ax = 0.f, ay = 0.f, az = 0.f, aw = 0.f;
    float scale = 0.f;
    if (node < n) {
      scale = ndv[node];
      int beg = row_ptr[node];
      int end = row_ptr[node + 1];
      int j = beg;
      for (; j + 16 <= end; j += 16) {  // 8 pair-loads in flight
        int s[16];
#pragma unroll
        for (int q = 0; q < 16; ++q) s[q] = adj[j + q];
        float4 v[8];
#pragma unroll
        for (int q = 0; q < 8; ++q) {
          int a = half ? s[2 * q + 1] : s[2 * q];
          v[q] = g4[(size_t)a * 32 + m];
        }
#pragma unroll
        for (int q = 0; q < 8; ++q) {
          ax += v[q].x; ay += v[q].y; az += v[q].z; aw += v[q].w;
        }
      }
      for (; j + 4 <= end; j += 4) {  // 2 pair-loads
        int s0 = adj[j], s1 = adj[j + 1], s2 = adj[j + 2], s3 = adj[j + 3];
        int a0 = half ? s1 : s0;
        int a1 = half ? s3 : s2;
        float4 v0 = g4[(size_t)a0 * 32 + m];
        float4 v1 = g4[(size_t)a1 * 32 + m];
        ax += v0.x + v1.x; ay += v0.y + v1.y;
        az += v0.z + v1.z; aw += v0.w + v1.w;
      }
      if (j + 2 <= end) {
        int s0 = adj[j], s1 = adj[j + 1];
        int a = half ? s1 : s0;
        float4 v = g4[(size_t)a * 32 + m];
        ax += v.x; ay += v.y; az += v.z; aw += v.w;
        j += 2;
      }
      if (j < end && half == 0) {
        int s0 = adj[j];
        float4 v = g4[(size_t)s0 * 32 + m];
        ax += v.x; ay += v.y; az += v.z; aw += v.w;
      }
    }
    ax += __shfl_xor(ax, 32, 64);
    ay += __shfl_xor(ay, 32, 64);
    az += __shfl_xor(az, 32, 64);
    aw += __shfl_xor(aw, 32, 64);
    if (half == 0)
      *(float4*)&Xs[r][m * 4] =
          make_float4(ax * scale, ay * scale, az * scale, aw * scale);
  }
  __syncthreads();

  int tx = tid & 31;   // col group: cols tx*4..tx*4+3
  int ty = tid >> 5;   // row group: rows ty*4..ty*4+3
  float acc[4][4] = {};
  const float4* wp0 = (const float4*)W + tx;
  for (int k4 = 0; k4 < DD / 4; ++k4) {
    const float4* wp = wp0 + (size_t)k4 * 4 * 32;
    float4 w0 = wp[0];
    float4 w1 = wp[32];
    float4 w2 = wp[64];
    float4 w3 = wp[96];
#pragma unroll
    for (int i = 0; i < 4; ++i) {
      float4 x = *(const float4*)&Xs[ty * 4 + i][k4 * 4];
      acc[i][0] = fmaf(x.x, w0.x, acc[i][0]);
      acc[i][1] = fmaf(x.x, w0.y, acc[i][1]);
      acc[i][2] = fmaf(x.x, w0.z, acc[i][2]);
      acc[i][3] = fmaf(x.x, w0.w, acc[i][3]);
      acc[i][0] = fmaf(x.y, w1.x, acc[i][0]);
      acc[i][1] = fmaf(x.y, w1.y, acc[i][1]);
      acc[i][2] = fmaf(x.y, w1.z, acc[i][2]);
      acc[i][3] = fmaf(x.y, w1.w, acc[i][3]);
      acc[i][0] = fmaf(x.z, w2.x, acc[i][0]);
      acc[i][1] = fmaf(x.z, w2.y, acc[i][1]);
      acc[i][2] = fmaf(x.z, w2.z, acc[i][2]);
      acc[i][3] = fmaf(x.z, w2.w, acc[i][3]);
      acc[i][0] = fmaf(x.w, w3.x, acc[i][0]);
      acc[i][1] = fmaf(x.w, w3.y, acc[i][1]);
      acc[i][2] = fmaf(x.w, w3.z, acc[i][2]);
      acc[i][3] = fmaf(x.w, w3.w, acc[i][3]);
    }
  }
  float4 bv = *(const float4*)(bias + tx * 4);
#pragma unroll
  for (int i = 0; i < 4; ++i) {
    int r = row0 + ty * 4 + i;
    if (r < n) {
      float4 o;
      o.x = fmaxf(acc[i][0] + bv.x, 0.f);
      o.y = fmaxf(acc[i][1] + bv.y, 0.f);
      o.z = fmaxf(acc[i][2] + bv.z, 0.f);
      o.w = fmaxf(acc[i][3] + bv.w, 0.f);
      if (!last) {
        float s = ns[r];
        o.x *= s; o.y *= s; o.z *= s; o.w *= s;
      }
      *(float4*)(gout + (size_t)r * DD + tx * 4) = o;
    }
  }
}

// ---------------- launch ----------------

extern "C" void kernel_launch(void* const* d_in, const int* in_sizes, int n_in,
                              void* d_out, int out_size, void* d_ws, size_t ws_size,
                              hipStream_t stream) {
  const float* feat = (const float*)d_in[0];
  const int* src = (const int*)d_in[1];
  const int* dst = (const int*)d_in[2];
  const float* W = (const float*)d_in[3];
  const float* b = (const float*)d_in[4];
  const int N = in_sizes[0] / DD;
  const int E = in_sizes[1];
  const int L = in_sizes[3] / (DD * DD);
  const int NW = (N + 1) >> 1;
  const int EC = (E + NBC - 1) / NBC;

  char* p = (char*)d_ws;
  auto alloc = [&](size_t bytes) {
    void* r = (void*)p;
    p += (bytes + 255) & ~(size_t)255;
    return r;
  };
  int* deg_in = (int*)alloc((size_t)N * 4);
  int* row_ptr = (int*)alloc(((size_t)N + 1) * 4);
  int* adj = (int*)alloc((size_t)E * 4);
  float* norm_src = (float*)alloc((size_t)N * 4);
  float* norm_dst = (float*)alloc((size_t)N * 4);
  int* bsum = (int*)alloc(((size_t)N / 2048 + 2) * 4);
  unsigned int* hsrc = (unsigned int*)alloc((size_t)NBC * NW * 4);
  unsigned int* hdst = (unsigned int*)alloc((size_t)NBC * NW * 4);
  float* hbuf = (float*)alloc((size_t)N * DD * 4);

  const int nb = (N + 2047) / 2048;
  const int nwb = (NW + 255) / 256;

  hist2_kernel<<<2 * NBC, 256, 0, stream>>>(src, dst, hsrc, hdst, E, N, EC);
  degnorm_kernel<<<nwb, 256, 0, stream>>>(hsrc, hdst, deg_in, norm_src, norm_dst, N);
  scan_partial_kernel<<<nb, 256, 0, stream>>>(deg_in, bsum, N);
  scan_bsum_kernel<<<1, 64, 0, stream>>>(bsum, nb);
  scan_final_kernel<<<nb, 256, 0, stream>>>(deg_in, bsum, row_ptr, N, E);
  chunkprefix_kernel<<<nwb, 256, 0, stream>>>(hdst, N);
  fillx_kernel<<<NBC, 256, 0, stream>>>(src, dst, hdst, row_ptr, adj, E, N, EC);

  float* out_f = (float*)d_out;
  // g0 -> hbuf; even layers hbuf->d_out, odd d_out->hbuf; L=5 ends in d_out.
  prescale_kernel<<<(N * 32 + 255) / 256, 256, 0, stream>>>(feat, norm_src, hbuf, N);
  for (int l = 0; l < L; ++l) {
    const float* gi = (l & 1) ? (const float*)out_f : (const float*)hbuf;
    float* go = (l & 1) ? hbuf : out_f;
    layer_kernel<<<(N + 31) / 32, 256, 0, stream>>>(
        gi, go, adj, row_ptr, norm_src, norm_dst, W + (size_t)l * DD * DD,
        b + (size_t)l * DD, N, (l == L - 1) ? 1 : 0);
  }
}

// Round 8
// 446.905 us; speedup vs baseline: 1.4998x; 1.4998x over previous
//
#include <hip/hip_runtime.h>

#define DD 128
#define NBC 64  // CSR edge chunks

// ---------------- bf16 helpers (RTN-even) ----------------
__device__ __forceinline__ unsigned int rtn16(float f) {
  unsigned int u = __float_as_uint(f);
  return (u + 0x7FFFu + ((u >> 16) & 1u)) >> 16;
}
#define UNPK_LO(u) __uint_as_float((u) << 16)
#define UNPK_HI(u) __uint_as_float((u) & 0xFFFF0000u)

// ---------------- CSR build (atomic-free at global scope) ----------------

__global__ __launch_bounds__(256) void hist2_kernel(const int* __restrict__ src,
                                                    const int* __restrict__ dst,
                                                    unsigned int* __restrict__ hsrc,
                                                    unsigned int* __restrict__ hdst,
                                                    int e, int n, int ec) {
  __shared__ unsigned int h[32768];  // 128 KB: supports n <= 65536
  int c = blockIdx.x & (NBC - 1);
  bool is_src = blockIdx.x >= NBC;
  const int* __restrict__ ids = is_src ? src : dst;
  unsigned int* __restrict__ out = is_src ? hsrc : hdst;
  int nw = (n + 1) >> 1;
  for (int w = threadIdx.x; w < nw; w += 256) h[w] = 0u;
  __syncthreads();
  int lo = c * ec;
  int hi = lo + ec; if (hi > e) hi = e;
  for (int i = lo + threadIdx.x; i < hi; i += 256) {
    int d = ids[i];
    atomicAdd(&h[d >> 1], (d & 1) ? 0x10000u : 1u);
  }
  __syncthreads();
  for (int w = threadIdx.x; w < nw; w += 256) out[(size_t)c * nw + w] = h[w];
}

// Merged: reduce hists -> deg/norms AND in-place chunk-exclusive-prefix of hdst.
__global__ __launch_bounds__(256) void degnorm_prefix_kernel(
    const unsigned int* __restrict__ hsrc, unsigned int* __restrict__ hdst,
    int* __restrict__ deg_in, float* __restrict__ norm_src,
    float* __restrict__ norm_dst, int n) {
  int nw = (n + 1) >> 1;
  int w = blockIdx.x * 256 + threadIdx.x;
  if (w >= nw) return;
  unsigned int slo = 0, shi = 0, dlo = 0, dhi = 0;
  for (int c = 0; c < NBC; ++c) {
    unsigned int a = hsrc[(size_t)c * nw + w];
    slo += a & 0xFFFFu; shi += a >> 16;
    size_t idx = (size_t)c * nw + w;
    unsigned int v = hdst[idx];
    hdst[idx] = dlo | (dhi << 16);  // exclusive prefix over chunks
    dlo += v & 0xFFFFu; dhi += v >> 16;
  }
  int n0 = 2 * w, n1 = 2 * w + 1;
  deg_in[n0] = (int)dlo;
  norm_src[n0] = 1.0f / sqrtf((float)(slo < 1u ? 1u : slo));
  norm_dst[n0] = 1.0f / sqrtf((float)(dlo < 1u ? 1u : dlo));
  if (n1 < n) {
    deg_in[n1] = (int)dhi;
    norm_src[n1] = 1.0f / sqrtf((float)(shi < 1u ? 1u : shi));
    norm_dst[n1] = 1.0f / sqrtf((float)(dhi < 1u ? 1u : dhi));
  }
}

// Multi-block scan, phase 1: per-block (2048-elem) sums.
__global__ __launch_bounds__(256) void scan_partial_kernel(const int* __restrict__ cnt,
                                                           int* __restrict__ bsum, int n) {
  __shared__ int ws[4];
  int tid = threadIdx.x;
  int base = blockIdx.x * 2048 + tid * 8;
  int s = 0;
#pragma unroll
  for (int i = 0; i < 8; ++i) {
    int id = base + i;
    if (id < n) s += cnt[id];
  }
#pragma unroll
  for (int d = 32; d; d >>= 1) s += __shfl_xor(s, d, 64);
  int lane = tid & 63, wid = tid >> 6;
  if (lane == 0) ws[wid] = s;
  __syncthreads();
  if (tid == 0) bsum[blockIdx.x] = ws[0] + ws[1] + ws[2] + ws[3];
}

// Phase 2: exclusive scan of block sums (single wave).
__global__ __launch_bounds__(64) void scan_bsum_kernel(int* __restrict__ bsum, int nb) {
  int lane = threadIdx.x;
  int run = 0;
  for (int base = 0; base < nb; base += 64) {
    int id = base + lane;
    int v = (id < nb) ? bsum[id] : 0;
    int sc = v;
#pragma unroll
    for (int d = 1; d < 64; d <<= 1) {
      int t = __shfl_up(sc, d, 64);
      if (lane >= d) sc += t;
    }
    if (id < nb) bsum[id] = run + sc - v;
    run += __shfl(sc, 63, 64);
  }
}

// Phase 3: scatter exclusive scan -> row_ptr.
__global__ __launch_bounds__(256) void scan_final_kernel(const int* __restrict__ cnt,
                                                         const int* __restrict__ bsum,
                                                         int* __restrict__ row_ptr,
                                                         int n, int e_total) {
  __shared__ int ws[4];
  int tid = threadIdx.x, lane = tid & 63, wid = tid >> 6;
  int base = blockIdx.x * 2048 + tid * 8;
  int v[8];
  int s = 0;
#pragma unroll
  for (int i = 0; i < 8; ++i) {
    int id = base + i;
    v[i] = (id < n) ? cnt[id] : 0;
    s += v[i];
  }
  int sc = s;
#pragma unroll
  for (int d = 1; d < 64; d <<= 1) {
    int t = __shfl_up(sc, d, 64);
    if (lane >= d) sc += t;
  }
  if (lane == 63) ws[wid] = sc;
  __syncthreads();
  int woff = 0;
  for (int w = 0; w < wid; ++w) woff += ws[w];
  int off = bsum[blockIdx.x] + woff + (sc - s);
#pragma unroll
  for (int i = 0; i < 8; ++i) {
    int id = base + i;
    if (id < n) {
      row_ptr[id] = off;
      off += v[i];
    }
  }
  if (blockIdx.x == 0 && tid == 0) row_ptr[n] = e_total;
}

// Fill adj: rank via LDS packed atomic; position = row_ptr[d] + chunk-prefix + rank.
__global__ __launch_bounds__(256) void fillx_kernel(const int* __restrict__ src,
                                                    const int* __restrict__ dst,
                                                    const unsigned int* __restrict__ hdst,
                                                    const int* __restrict__ row_ptr,
                                                    int* __restrict__ adj,
                                                    int e, int n, int ec) {
  __shared__ unsigned int h[32768];
  int c = blockIdx.x;
  int nw = (n + 1) >> 1;
  for (int w = threadIdx.x; w < nw; w += 256) h[w] = 0u;
  __syncthreads();
  int lo = c * ec;
  int hi = lo + ec; if (hi > e) hi = e;
  for (int i = lo + threadIdx.x; i < hi; i += 256) {
    int s = src[i];
    int d = dst[i];
    unsigned int old = atomicAdd(&h[d >> 1], (d & 1) ? 0x10000u : 1u);
    unsigned int rank = (d & 1) ? (old >> 16) : (old & 0xFFFFu);
    unsigned int pre = hdst[(size_t)c * nw + (d >> 1)];
    pre = (d & 1) ? (pre >> 16) : (pre & 0xFFFFu);
    adj[row_ptr[d] + (int)pre + (int)rank] = s;
  }
}

// g[i,:] = bf16(feat[i,:] * norm_src[i])
__global__ __launch_bounds__(256) void prescale_kernel(const float* __restrict__ feat,
                                                       const float* __restrict__ ns,
                                                       unsigned short* __restrict__ g,
                                                       int n) {
  int i = blockIdx.x * 256 + threadIdx.x;  // float4 index
  if (i < n * 32) {
    float4 v = ((const float4*)feat)[i];
    float s = ns[i >> 5];
    unsigned int p0 = rtn16(v.x * s), p1 = rtn16(v.y * s);
    unsigned int p2 = rtn16(v.z * s), p3 = rtn16(v.w * s);
    ((uint2*)g)[i] = make_uint2(p0 | (p1 << 16), p2 | (p3 << 16));
  }
}

// ---------------- fused layer: agg (bf16 gather-sum) + f32 gemm + relu -------
// T[r,:] = nd[r] * sum_{s in adj[r]} unpack_bf16(gin[s,:])   (f32 accumulate)
// out    = relu(T @ W + b); intermediate layers store bf16*ns, last stores f32.
// Quad-packed gather: 16 lanes x uint4 = one 256B bf16 row; 4 edges per
// wave-instruction, 4 row-loads in flight. Reduce via shfl_xor(16,32).
__global__ __launch_bounds__(256) void layer_kernel(const unsigned short* __restrict__ gin,
                                                    unsigned short* __restrict__ goutb,
                                                    float* __restrict__ goutf,
                                                    const int* __restrict__ adj,
                                                    const int* __restrict__ row_ptr,
                                                    const float* __restrict__ ns,
                                                    const float* __restrict__ ndv,
                                                    const float* __restrict__ W,
                                                    const float* __restrict__ bias,
                                                    int n, int last) {
  __shared__ float Xs[32][DD];
  int tid = threadIdx.x;
  int lane = tid & 63;
  int wv = tid >> 6;
  int m4 = lane & 15;   // 16B chunk of the 256B row
  int q = lane >> 4;    // quarter: which of 4 concurrent edges
  int row0 = blockIdx.x * 32;
  const uint4* g4 = (const uint4*)gin;

  for (int r = wv; r < 32; r += 4) {
    int node = row0 + r;
    float a0 = 0.f, a1 = 0.f, a2 = 0.f, a3 = 0.f;
    float a4 = 0.f, a5 = 0.f, a6 = 0.f, a7 = 0.f;
    float scale = 0.f;
#define ACC8(v)                                        \
  a0 += UNPK_LO(v.x); a1 += UNPK_HI(v.x);              \
  a2 += UNPK_LO(v.y); a3 += UNPK_HI(v.y);              \
  a4 += UNPK_LO(v.z); a5 += UNPK_HI(v.z);              \
  a6 += UNPK_LO(v.w); a7 += UNPK_HI(v.w);
    if (node < n) {
      scale = ndv[node];
      int beg = row_ptr[node];
      int end = row_ptr[node + 1];
      int j = beg;
      for (; j + 16 <= end; j += 16) {  // 4 row-loads in flight
        int e0 = adj[j + q];
        int e1 = adj[j + 4 + q];
        int e2 = adj[j + 8 + q];
        int e3 = adj[j + 12 + q];
        uint4 v0 = g4[(size_t)e0 * 16 + m4];
        uint4 v1 = g4[(size_t)e1 * 16 + m4];
        uint4 v2 = g4[(size_t)e2 * 16 + m4];
        uint4 v3 = g4[(size_t)e3 * 16 + m4];
        ACC8(v0); ACC8(v1); ACC8(v2); ACC8(v3);
      }
      for (; j + 4 <= end; j += 4) {
        int e0 = adj[j + q];
        uint4 v0 = g4[(size_t)e0 * 16 + m4];
        ACC8(v0);
      }
      int rem = end - j;
      if (q < rem) {
        int e0 = adj[j + q];
        uint4 v0 = g4[(size_t)e0 * 16 + m4];
        ACC8(v0);
      }
    }
#undef ACC8
    // sum quarters: lanes {m4, m4+16, m4+32, m4+48}
    a0 += __shfl_xor(a0, 16, 64); a0 += __shfl_xor(a0, 32, 64);
    a1 += __shfl_xor(a1, 16, 64); a1 += __shfl_xor(a1, 32, 64);
    a2 += __shfl_xor(a2, 16, 64); a2 += __shfl_xor(a2, 32, 64);
    a3 += __shfl_xor(a3, 16, 64); a3 += __shfl_xor(a3, 32, 64);
    a4 += __shfl_xor(a4, 16, 64); a4 += __shfl_xor(a4, 32, 64);
    a5 += __shfl_xor(a5, 16, 64); a5 += __shfl_xor(a5, 32, 64);
    a6 += __shfl_xor(a6, 16, 64); a6 += __shfl_xor(a6, 32, 64);
    a7 += __shfl_xor(a7, 16, 64); a7 += __shfl_xor(a7, 32, 64);
    if (q == 0) {
      float* xp = &Xs[r][m4 * 8];
      xp[0] = a0 * scale; xp[1] = a1 * scale;
      xp[2] = a2 * scale; xp[3] = a3 * scale;
      xp[4] = a4 * scale; xp[5] = a5 * scale;
      xp[6] = a6 * scale; xp[7] = a7 * scale;
    }
  }
  __syncthreads();

  int tx = tid & 31;   // col group: cols tx*4..tx*4+3
  int ty = tid >> 5;   // row group: rows ty*4..ty*4+3
  float acc[4][4] = {};
  const float4* wp0 = (const float4*)W + tx;
  for (int k4 = 0; k4 < DD / 4; ++k4) {
    const float4* wp = wp0 + (size_t)k4 * 4 * 32;
    float4 w0 = wp[0];
    float4 w1 = wp[32];
    float4 w2 = wp[64];
    float4 w3 = wp[96];
#pragma unroll
    for (int i = 0; i < 4; ++i) {
      float4 x = *(const float4*)&Xs[ty * 4 + i][k4 * 4];
      acc[i][0] = fmaf(x.x, w0.x, acc[i][0]);
      acc[i][1] = fmaf(x.x, w0.y, acc[i][1]);
      acc[i][2] = fmaf(x.x, w0.z, acc[i][2]);
      acc[i][3] = fmaf(x.x, w0.w, acc[i][3]);
      acc[i][0] = fmaf(x.y, w1.x, acc[i][0]);
      acc[i][1] = fmaf(x.y, w1.y, acc[i][1]);
      acc[i][2] = fmaf(x.y, w1.z, acc[i][2]);
      acc[i][3] = fmaf(x.y, w1.w, acc[i][3]);
      acc[i][0] = fmaf(x.z, w2.x, acc[i][0]);
      acc[i][1] = fmaf(x.z, w2.y, acc[i][1]);
      acc[i][2] = fmaf(x.z, w2.z, acc[i][2]);
      acc[i][3] = fmaf(x.z, w2.w, acc[i][3]);
      acc[i][0] = fmaf(x.w, w3.x, acc[i][0]);
      acc[i][1] = fmaf(x.w, w3.y, acc[i][1]);
      acc[i][2] = fmaf(x.w, w3.z, acc[i][2]);
      acc[i][3] = fmaf(x.w, w3.w, acc[i][3]);
    }
  }
  float4 bv = *(const float4*)(bias + tx * 4);
#pragma unroll
  for (int i = 0; i < 4; ++i) {
    int r = row0 + ty * 4 + i;
    if (r < n) {
      float4 o;
      o.x = fmaxf(acc[i][0] + bv.x, 0.f);
      o.y = fmaxf(acc[i][1] + bv.y, 0.f);
      o.z = fmaxf(acc[i][2] + bv.z, 0.f);
      o.w = fmaxf(acc[i][3] + bv.w, 0.f);
      if (last) {
        *(float4*)(goutf + (size_t)r * DD + tx * 4) = o;
      } else {
        float s = ns[r];
        unsigned int p0 = rtn16(o.x * s), p1 = rtn16(o.y * s);
        unsigned int p2 = rtn16(o.z * s), p3 = rtn16(o.w * s);
        ((uint2*)(goutb + (size_t)r * DD))[tx] =
            make_uint2(p0 | (p1 << 16), p2 | (p3 << 16));
      }
    }
  }
}

// ---------------- launch ----------------

extern "C" void kernel_launch(void* const* d_in, const int* in_sizes, int n_in,
                              void* d_out, int out_size, void* d_ws, size_t ws_size,
                              hipStream_t stream) {
  const float* feat = (const float*)d_in[0];
  const int* src = (const int*)d_in[1];
  const int* dst = (const int*)d_in[2];
  const float* W = (const float*)d_in[3];
  const float* b = (const float*)d_in[4];
  const int N = in_sizes[0] / DD;
  const int E = in_sizes[1];
  const int L = in_sizes[3] / (DD * DD);
  const int NW = (N + 1) >> 1;
  const int EC = (E + NBC - 1) / NBC;

  char* p = (char*)d_ws;
  auto alloc = [&](size_t bytes) {
    void* r = (void*)p;
    p += (bytes + 255) & ~(size_t)255;
    return r;
  };
  int* deg_in = (int*)alloc((size_t)N * 4);
  int* row_ptr = (int*)alloc(((size_t)N + 1) * 4);
  int* adj = (int*)alloc((size_t)E * 4);
  float* norm_src = (float*)alloc((size_t)N * 4);
  float* norm_dst = (float*)alloc((size_t)N * 4);
  int* bsum = (int*)alloc(((size_t)N / 2048 + 2) * 4);
  unsigned int* hsrc = (unsigned int*)alloc((size_t)NBC * NW * 4);
  unsigned int* hdst = (unsigned int*)alloc((size_t)NBC * NW * 4);
  unsigned short* ga = (unsigned short*)alloc((size_t)N * DD * 2);
  unsigned short* gb = (unsigned short*)alloc((size_t)N * DD * 2);

  const int nb = (N + 2047) / 2048;
  const int nwb = (NW + 255) / 256;

  hist2_kernel<<<2 * NBC, 256, 0, stream>>>(src, dst, hsrc, hdst, E, N, EC);
  degnorm_prefix_kernel<<<nwb, 256, 0, stream>>>(hsrc, hdst, deg_in, norm_src,
                                                 norm_dst, N);
  scan_partial_kernel<<<nb, 256, 0, stream>>>(deg_in, bsum, N);
  scan_bsum_kernel<<<1, 64, 0, stream>>>(bsum, nb);
  scan_final_kernel<<<nb, 256, 0, stream>>>(deg_in, bsum, row_ptr, N, E);
  fillx_kernel<<<NBC, 256, 0, stream>>>(src, dst, hdst, row_ptr, adj, E, N, EC);

  float* out_f = (float*)d_out;
  prescale_kernel<<<(N * 32 + 255) / 256, 256, 0, stream>>>(feat, norm_src, ga, N);
  for (int l = 0; l < L; ++l) {
    const unsigned short* gi = (l & 1) ? gb : ga;
    unsigned short* go = (l & 1) ? ga : gb;
    int last = (l == L - 1) ? 1 : 0;
    layer_kernel<<<(N + 31) / 32, 256, 0, stream>>>(
        gi, go, out_f, adj, row_ptr, norm_src, norm_dst,
        W + (size_t)l * DD * DD, b + (size_t)l * DD, N, last);
  }
}

// Round 9
// 435.190 us; speedup vs baseline: 1.5401x; 1.0269x over previous
//
#include <hip/hip_runtime.h>

#define DD 128
#define NBC 64  // CSR edge chunks

// ---------------- bf16 helpers (RTN-even) ----------------
__device__ __forceinline__ unsigned int rtn16(float f) {
  unsigned int u = __float_as_uint(f);
  return (u + 0x7FFFu + ((u >> 16) & 1u)) >> 16;
}
#define UNPK_LO(u) __uint_as_float((u) << 16)
#define UNPK_HI(u) __uint_as_float((u) & 0xFFFF0000u)

// ---------------- CSR build (atomic-free at global scope) ----------------

__global__ __launch_bounds__(256) void hist2_kernel(const int* __restrict__ src,
                                                    const int* __restrict__ dst,
                                                    unsigned int* __restrict__ hsrc,
                                                    unsigned int* __restrict__ hdst,
                                                    int e, int n, int ec) {
  __shared__ unsigned int h[32768];  // 128 KB: supports n <= 65536
  int c = blockIdx.x & (NBC - 1);
  bool is_src = blockIdx.x >= NBC;
  const int* __restrict__ ids = is_src ? src : dst;
  unsigned int* __restrict__ out = is_src ? hsrc : hdst;
  int nw = (n + 1) >> 1;
  for (int w = threadIdx.x; w < nw; w += 256) h[w] = 0u;
  __syncthreads();
  int lo = c * ec;
  int hi = lo + ec; if (hi > e) hi = e;
  for (int i = lo + threadIdx.x; i < hi; i += 256) {
    int d = ids[i];
    atomicAdd(&h[d >> 1], (d & 1) ? 0x10000u : 1u);
  }
  __syncthreads();
  for (int w = threadIdx.x; w < nw; w += 256) out[(size_t)c * nw + w] = h[w];
}

// Merged: reduce hists -> deg/norms AND in-place chunk-exclusive-prefix of hdst.
__global__ __launch_bounds__(256) void degnorm_prefix_kernel(
    const unsigned int* __restrict__ hsrc, unsigned int* __restrict__ hdst,
    int* __restrict__ deg_in, float* __restrict__ norm_src,
    float* __restrict__ norm_dst, int n) {
  int nw = (n + 1) >> 1;
  int w = blockIdx.x * 256 + threadIdx.x;
  if (w >= nw) return;
  unsigned int slo = 0, shi = 0, dlo = 0, dhi = 0;
  for (int c = 0; c < NBC; ++c) {
    unsigned int a = hsrc[(size_t)c * nw + w];
    slo += a & 0xFFFFu; shi += a >> 16;
    size_t idx = (size_t)c * nw + w;
    unsigned int v = hdst[idx];
    hdst[idx] = dlo | (dhi << 16);  // exclusive prefix over chunks
    dlo += v & 0xFFFFu; dhi += v >> 16;
  }
  int n0 = 2 * w, n1 = 2 * w + 1;
  deg_in[n0] = (int)dlo;
  norm_src[n0] = 1.0f / sqrtf((float)(slo < 1u ? 1u : slo));
  norm_dst[n0] = 1.0f / sqrtf((float)(dlo < 1u ? 1u : dlo));
  if (n1 < n) {
    deg_in[n1] = (int)dhi;
    norm_src[n1] = 1.0f / sqrtf((float)(shi < 1u ? 1u : shi));
    norm_dst[n1] = 1.0f / sqrtf((float)(dhi < 1u ? 1u : dhi));
  }
}

// Multi-block scan, phase 1: per-block (2048-elem) sums.
__global__ __launch_bounds__(256) void scan_partial_kernel(const int* __restrict__ cnt,
                                                           int* __restrict__ bsum, int n) {
  __shared__ int ws[4];
  int tid = threadIdx.x;
  int base = blockIdx.x * 2048 + tid * 8;
  int s = 0;
#pragma unroll
  for (int i = 0; i < 8; ++i) {
    int id = base + i;
    if (id < n) s += cnt[id];
  }
#pragma unroll
  for (int d = 32; d; d >>= 1) s += __shfl_xor(s, d, 64);
  int lane = tid & 63, wid = tid >> 6;
  if (lane == 0) ws[wid] = s;
  __syncthreads();
  if (tid == 0) bsum[blockIdx.x] = ws[0] + ws[1] + ws[2] + ws[3];
}

// Phase 2: exclusive scan of block sums (single wave).
__global__ __launch_bounds__(64) void scan_bsum_kernel(int* __restrict__ bsum, int nb) {
  int lane = threadIdx.x;
  int run = 0;
  for (int base = 0; base < nb; base += 64) {
    int id = base + lane;
    int v = (id < nb) ? bsum[id] : 0;
    int sc = v;
#pragma unroll
    for (int d = 1; d < 64; d <<= 1) {
      int t = __shfl_up(sc, d, 64);
      if (lane >= d) sc += t;
    }
    if (id < nb) bsum[id] = run + sc - v;
    run += __shfl(sc, 63, 64);
  }
}

// Phase 3: scatter exclusive scan -> row_ptr.
__global__ __launch_bounds__(256) void scan_final_kernel(const int* __restrict__ cnt,
                                                         const int* __restrict__ bsum,
                                                         int* __restrict__ row_ptr,
                                                         int n, int e_total) {
  __shared__ int ws[4];
  int tid = threadIdx.x, lane = tid & 63, wid = tid >> 6;
  int base = blockIdx.x * 2048 + tid * 8;
  int v[8];
  int s = 0;
#pragma unroll
  for (int i = 0; i < 8; ++i) {
    int id = base + i;
    v[i] = (id < n) ? cnt[id] : 0;
    s += v[i];
  }
  int sc = s;
#pragma unroll
  for (int d = 1; d < 64; d <<= 1) {
    int t = __shfl_up(sc, d, 64);
    if (lane >= d) sc += t;
  }
  if (lane == 63) ws[wid] = sc;
  __syncthreads();
  int woff = 0;
  for (int w = 0; w < wid; ++w) woff += ws[w];
  int off = bsum[blockIdx.x] + woff + (sc - s);
#pragma unroll
  for (int i = 0; i < 8; ++i) {
    int id = base + i;
    if (id < n) {
      row_ptr[id] = off;
      off += v[i];
    }
  }
  if (blockIdx.x == 0 && tid == 0) row_ptr[n] = e_total;
}

// Fill adj: rank via LDS packed atomic; position = row_ptr[d] + chunk-prefix + rank.
__global__ __launch_bounds__(256) void fillx_kernel(const int* __restrict__ src,
                                                    const int* __restrict__ dst,
                                                    const unsigned int* __restrict__ hdst,
                                                    const int* __restrict__ row_ptr,
                                                    int* __restrict__ adj,
                                                    int e, int n, int ec) {
  __shared__ unsigned int h[32768];
  int c = blockIdx.x;
  int nw = (n + 1) >> 1;
  for (int w = threadIdx.x; w < nw; w += 256) h[w] = 0u;
  __syncthreads();
  int lo = c * ec;
  int hi = lo + ec; if (hi > e) hi = e;
  for (int i = lo + threadIdx.x; i < hi; i += 256) {
    int s = src[i];
    int d = dst[i];
    unsigned int old = atomicAdd(&h[d >> 1], (d & 1) ? 0x10000u : 1u);
    unsigned int rank = (d & 1) ? (old >> 16) : (old & 0xFFFFu);
    unsigned int pre = hdst[(size_t)c * nw + (d >> 1)];
    pre = (d & 1) ? (pre >> 16) : (pre & 0xFFFFu);
    adj[row_ptr[d] + (int)pre + (int)rank] = s;
  }
}

// g[i,:] = bf16(feat[i,:] * norm_src[i]); row n of BOTH buffers = zeros
// (zero-row pad consumed by the uniform gather loop).
__global__ __launch_bounds__(256) void prescale_kernel(const float* __restrict__ feat,
                                                       const float* __restrict__ ns,
                                                       unsigned short* __restrict__ ga,
                                                       unsigned short* __restrict__ gb,
                                                       int n) {
  int i = blockIdx.x * 256 + threadIdx.x;  // uint2 (8-bf16) index
  if (i >= (n + 1) * 32) return;
  if (i >= n * 32) {  // zero row
    ((uint2*)ga)[i] = make_uint2(0u, 0u);
    ((uint2*)gb)[i] = make_uint2(0u, 0u);
    return;
  }
  float4 v = ((const float4*)feat)[i];
  float s = ns[i >> 5];
  unsigned int p0 = rtn16(v.x * s), p1 = rtn16(v.y * s);
  unsigned int p2 = rtn16(v.z * s), p3 = rtn16(v.w * s);
  ((uint2*)ga)[i] = make_uint2(p0 | (p1 << 16), p2 | (p3 << 16));
}

// ---------------- fused layer: agg (bf16 gather-sum) + f32 gemm + relu -------
// T[r,:] = nd[r] * sum_{s in adj[r]} unpack_bf16(gin[s,:])   (f32 accumulate)
// out    = relu(T @ W + b); intermediate layers store bf16*ns, last stores f32.
// Quad-packed gather: 16 lanes x uint4 = one 256B bf16 row; 4 edges per
// wave-instruction. UNIFORM 16-edge loop: out-of-range slots read the
// all-zeros row n (L1-resident) -> every node runs 4 row-loads in flight,
// no serial tail. Reduce via shfl_xor(16,32).
__global__ __launch_bounds__(256) void layer_kernel(const unsigned short* __restrict__ gin,
                                                    unsigned short* __restrict__ goutb,
                                                    float* __restrict__ goutf,
                                                    const int* __restrict__ adj,
                                                    const int* __restrict__ row_ptr,
                                                    const float* __restrict__ ns,
                                                    const float* __restrict__ ndv,
                                                    const float* __restrict__ W,
                                                    const float* __restrict__ bias,
                                                    int n, int last) {
  __shared__ float Xs[32][DD];
  int tid = threadIdx.x;
  int lane = tid & 63;
  int wv = tid >> 6;
  int m4 = lane & 15;   // 16B chunk of the 256B row
  int q = lane >> 4;    // quarter: which of 4 concurrent edges
  int row0 = blockIdx.x * 32;
  const uint4* g4 = (const uint4*)gin;

  for (int r = wv; r < 32; r += 4) {
    int node = row0 + r;
    float a0 = 0.f, a1 = 0.f, a2 = 0.f, a3 = 0.f;
    float a4 = 0.f, a5 = 0.f, a6 = 0.f, a7 = 0.f;
    float scale = 0.f;
#define ACC8(v)                                        \
  a0 += UNPK_LO(v.x); a1 += UNPK_HI(v.x);              \
  a2 += UNPK_LO(v.y); a3 += UNPK_HI(v.y);              \
  a4 += UNPK_LO(v.z); a5 += UNPK_HI(v.z);              \
  a6 += UNPK_LO(v.w); a7 += UNPK_HI(v.w);
    if (node < n) {
      scale = ndv[node];
      int beg = row_ptr[node];
      int end = row_ptr[node + 1];
      for (int j = beg; j < end; j += 16) {  // uniform: 4 row-loads in flight
        int i0 = j + q;
        int i1 = j + 4 + q;
        int i2 = j + 8 + q;
        int i3 = j + 12 + q;
        int e0 = (i0 < end) ? adj[i0] : n;
        int e1 = (i1 < end) ? adj[i1] : n;
        int e2 = (i2 < end) ? adj[i2] : n;
        int e3 = (i3 < end) ? adj[i3] : n;
        uint4 v0 = g4[(size_t)e0 * 16 + m4];
        uint4 v1 = g4[(size_t)e1 * 16 + m4];
        uint4 v2 = g4[(size_t)e2 * 16 + m4];
        uint4 v3 = g4[(size_t)e3 * 16 + m4];
        ACC8(v0); ACC8(v1); ACC8(v2); ACC8(v3);
      }
    }
#undef ACC8
    // sum quarters: lanes {m4, m4+16, m4+32, m4+48}
    a0 += __shfl_xor(a0, 16, 64); a0 += __shfl_xor(a0, 32, 64);
    a1 += __shfl_xor(a1, 16, 64); a1 += __shfl_xor(a1, 32, 64);
    a2 += __shfl_xor(a2, 16, 64); a2 += __shfl_xor(a2, 32, 64);
    a3 += __shfl_xor(a3, 16, 64); a3 += __shfl_xor(a3, 32, 64);
    a4 += __shfl_xor(a4, 16, 64); a4 += __shfl_xor(a4, 32, 64);
    a5 += __shfl_xor(a5, 16, 64); a5 += __shfl_xor(a5, 32, 64);
    a6 += __shfl_xor(a6, 16, 64); a6 += __shfl_xor(a6, 32, 64);
    a7 += __shfl_xor(a7, 16, 64); a7 += __shfl_xor(a7, 32, 64);
    if (q == 0) {
      float* xp = &Xs[r][m4 * 8];
      xp[0] = a0 * scale; xp[1] = a1 * scale;
      xp[2] = a2 * scale; xp[3] = a3 * scale;
      xp[4] = a4 * scale; xp[5] = a5 * scale;
      xp[6] = a6 * scale; xp[7] = a7 * scale;
    }
  }
  __syncthreads();

  int tx = tid & 31;   // col group: cols tx*4..tx*4+3
  int ty = tid >> 5;   // row group: rows ty*4..ty*4+3
  float acc[4][4] = {};
  const float4* wp0 = (const float4*)W + tx;
  for (int k4 = 0; k4 < DD / 4; ++k4) {
    const float4* wp = wp0 + (size_t)k4 * 4 * 32;
    float4 w0 = wp[0];
    float4 w1 = wp[32];
    float4 w2 = wp[64];
    float4 w3 = wp[96];
#pragma unroll
    for (int i = 0; i < 4; ++i) {
      float4 x = *(const float4*)&Xs[ty * 4 + i][k4 * 4];
      acc[i][0] = fmaf(x.x, w0.x, acc[i][0]);
      acc[i][1] = fmaf(x.x, w0.y, acc[i][1]);
      acc[i][2] = fmaf(x.x, w0.z, acc[i][2]);
      acc[i][3] = fmaf(x.x, w0.w, acc[i][3]);
      acc[i][0] = fmaf(x.y, w1.x, acc[i][0]);
      acc[i][1] = fmaf(x.y, w1.y, acc[i][1]);
      acc[i][2] = fmaf(x.y, w1.z, acc[i][2]);
      acc[i][3] = fmaf(x.y, w1.w, acc[i][3]);
      acc[i][0] = fmaf(x.z, w2.x, acc[i][0]);
      acc[i][1] = fmaf(x.z, w2.y, acc[i][1]);
      acc[i][2] = fmaf(x.z, w2.z, acc[i][2]);
      acc[i][3] = fmaf(x.z, w2.w, acc[i][3]);
      acc[i][0] = fmaf(x.w, w3.x, acc[i][0]);
      acc[i][1] = fmaf(x.w, w3.y, acc[i][1]);
      acc[i][2] = fmaf(x.w, w3.z, acc[i][2]);
      acc[i][3] = fmaf(x.w, w3.w, acc[i][3]);
    }
  }
  float4 bv = *(const float4*)(bias + tx * 4);
#pragma unroll
  for (int i = 0; i < 4; ++i) {
    int r = row0 + ty * 4 + i;
    if (r < n) {
      float4 o;
      o.x = fmaxf(acc[i][0] + bv.x, 0.f);
      o.y = fmaxf(acc[i][1] + bv.y, 0.f);
      o.z = fmaxf(acc[i][2] + bv.z, 0.f);
      o.w = fmaxf(acc[i][3] + bv.w, 0.f);
      if (last) {
        *(float4*)(goutf + (size_t)r * DD + tx * 4) = o;
      } else {
        float s = ns[r];
        unsigned int p0 = rtn16(o.x * s), p1 = rtn16(o.y * s);
        unsigned int p2 = rtn16(o.z * s), p3 = rtn16(o.w * s);
        ((uint2*)(goutb + (size_t)r * DD))[tx] =
            make_uint2(p0 | (p1 << 16), p2 | (p3 << 16));
      }
    }
  }
}

// ---------------- launch ----------------

extern "C" void kernel_launch(void* const* d_in, const int* in_sizes, int n_in,
                              void* d_out, int out_size, void* d_ws, size_t ws_size,
                              hipStream_t stream) {
  const float* feat = (const float*)d_in[0];
  const int* src = (const int*)d_in[1];
  const int* dst = (const int*)d_in[2];
  const float* W = (const float*)d_in[3];
  const float* b = (const float*)d_in[4];
  const int N = in_sizes[0] / DD;
  const int E = in_sizes[1];
  const int L = in_sizes[3] / (DD * DD);
  const int NW = (N + 1) >> 1;
  const int EC = (E + NBC - 1) / NBC;

  char* p = (char*)d_ws;
  auto alloc = [&](size_t bytes) {
    void* r = (void*)p;
    p += (bytes + 255) & ~(size_t)255;
    return r;
  };
  int* deg_in = (int*)alloc((size_t)N * 4);
  int* row_ptr = (int*)alloc(((size_t)N + 1) * 4);
  int* adj = (int*)alloc((size_t)E * 4);
  float* norm_src = (float*)alloc((size_t)N * 4);
  float* norm_dst = (float*)alloc((size_t)N * 4);
  int* bsum = (int*)alloc(((size_t)N / 2048 + 2) * 4);
  unsigned int* hsrc = (unsigned int*)alloc((size_t)NBC * NW * 4);
  unsigned int* hdst = (unsigned int*)alloc((size_t)NBC * NW * 4);
  unsigned short* ga = (unsigned short*)alloc(((size_t)N + 1) * DD * 2);
  unsigned short* gb = (unsigned short*)alloc(((size_t)N + 1) * DD * 2);

  const int nb = (N + 2047) / 2048;
  const int nwb = (NW + 255) / 256;

  hist2_kernel<<<2 * NBC, 256, 0, stream>>>(src, dst, hsrc, hdst, E, N, EC);
  degnorm_prefix_kernel<<<nwb, 256, 0, stream>>>(hsrc, hdst, deg_in, norm_src,
                                                 norm_dst, N);
  scan_partial_kernel<<<nb, 256, 0, stream>>>(deg_in, bsum, N);
  scan_bsum_kernel<<<1, 64, 0, stream>>>(bsum, nb);
  scan_final_kernel<<<nb, 256, 0, stream>>>(deg_in, bsum, row_ptr, N, E);
  fillx_kernel<<<NBC, 256, 0, stream>>>(src, dst, hdst, row_ptr, adj, E, N, EC);

  float* out_f = (float*)d_out;
  prescale_kernel<<<((N + 1) * 32 + 255) / 256, 256, 0, stream>>>(feat, norm_src,
                                                                  ga, gb, N);
  for (int l = 0; l < L; ++l) {
    const unsigned short* gi = (l & 1) ? gb : ga;
    unsigned short* go = (l & 1) ? ga : gb;
    int last = (l == L - 1) ? 1 : 0;
    layer_kernel<<<(N + 31) / 32, 256, 0, stream>>>(
        gi, go, out_f, adj, row_ptr, norm_src, norm_dst,
        W + (size_t)l * DD * DD, b + (size_t)l * DD, N, last);
  }
}

// Round 10
// 434.313 us; speedup vs baseline: 1.5432x; 1.0020x over previous
//
#include <hip/hip_runtime.h>

#define DD 128
#define NBC 64  // CSR edge chunks

// ---------------- bf16 helpers (RTN-even) ----------------
__device__ __forceinline__ unsigned int rtn16(float f) {
  unsigned int u = __float_as_uint(f);
  return (u + 0x7FFFu + ((u >> 16) & 1u)) >> 16;
}
#define UNPK_LO(u) __uint_as_float((u) << 16)
#define UNPK_HI(u) __uint_as_float((u) & 0xFFFF0000u)

// ---------------- CSR build (atomic-free at global scope) ----------------

__global__ __launch_bounds__(256) void hist2_kernel(const int* __restrict__ src,
                                                    const int* __restrict__ dst,
                                                    unsigned int* __restrict__ hsrc,
                                                    unsigned int* __restrict__ hdst,
                                                    int e, int n, int ec) {
  __shared__ unsigned int h[32768];  // 128 KB: supports n <= 65536
  int c = blockIdx.x & (NBC - 1);
  bool is_src = blockIdx.x >= NBC;
  const int* __restrict__ ids = is_src ? src : dst;
  unsigned int* __restrict__ out = is_src ? hsrc : hdst;
  int nw = (n + 1) >> 1;
  for (int w = threadIdx.x; w < nw; w += 256) h[w] = 0u;
  __syncthreads();
  int lo = c * ec;
  int hi = lo + ec; if (hi > e) hi = e;
  for (int i = lo + threadIdx.x; i < hi; i += 256) {
    int d = ids[i];
    atomicAdd(&h[d >> 1], (d & 1) ? 0x10000u : 1u);
  }
  __syncthreads();
  for (int w = threadIdx.x; w < nw; w += 256) out[(size_t)c * nw + w] = h[w];
}

// Merged: reduce hists -> deg/norms, in-place chunk-exclusive-prefix of hdst,
// AND per-block (512-node) degree sums -> bsum (feeds the scan directly).
__global__ __launch_bounds__(256) void degnorm_prefix_kernel(
    const unsigned int* __restrict__ hsrc, unsigned int* __restrict__ hdst,
    int* __restrict__ deg_in, float* __restrict__ norm_src,
    float* __restrict__ norm_dst, int* __restrict__ bsum, int n) {
  __shared__ int ws[4];
  int nw = (n + 1) >> 1;
  int tid = threadIdx.x, lane = tid & 63, wid = tid >> 6;
  int w = blockIdx.x * 256 + tid;
  unsigned int slo = 0, shi = 0, dlo = 0, dhi = 0;
  if (w < nw) {
    for (int c = 0; c < NBC; ++c) {
      unsigned int a = hsrc[(size_t)c * nw + w];
      slo += a & 0xFFFFu; shi += a >> 16;
      size_t idx = (size_t)c * nw + w;
      unsigned int v = hdst[idx];
      hdst[idx] = dlo | (dhi << 16);  // exclusive prefix over chunks
      dlo += v & 0xFFFFu; dhi += v >> 16;
    }
    int n0 = 2 * w, n1 = 2 * w + 1;
    deg_in[n0] = (int)dlo;
    norm_src[n0] = 1.0f / sqrtf((float)(slo < 1u ? 1u : slo));
    norm_dst[n0] = 1.0f / sqrtf((float)(dlo < 1u ? 1u : dlo));
    if (n1 < n) {
      deg_in[n1] = (int)dhi;
      norm_src[n1] = 1.0f / sqrtf((float)(shi < 1u ? 1u : shi));
      norm_dst[n1] = 1.0f / sqrtf((float)(dhi < 1u ? 1u : dhi));
    } else {
      dhi = 0;
    }
  }
  int s = (int)(dlo + dhi);
#pragma unroll
  for (int d = 32; d; d >>= 1) s += __shfl_xor(s, d, 64);
  if (lane == 0) ws[wid] = s;
  __syncthreads();
  if (tid == 0) bsum[blockIdx.x] = ws[0] + ws[1] + ws[2] + ws[3];
}

// Exclusive scan of block sums (single wave).
__global__ __launch_bounds__(64) void scan_bsum_kernel(int* __restrict__ bsum, int nb) {
  int lane = threadIdx.x;
  int run = 0;
  for (int base = 0; base < nb; base += 64) {
    int id = base + lane;
    int v = (id < nb) ? bsum[id] : 0;
    int sc = v;
#pragma unroll
    for (int d = 1; d < 64; d <<= 1) {
      int t = __shfl_up(sc, d, 64);
      if (lane >= d) sc += t;
    }
    if (id < nb) bsum[id] = run + sc - v;
    run += __shfl(sc, 63, 64);
  }
}

// Final scatter: 512 nodes per block (matches degnorm blocks), 2 nodes/thread.
__global__ __launch_bounds__(256) void scan_final_kernel(const int* __restrict__ cnt,
                                                         const int* __restrict__ bsum,
                                                         int* __restrict__ row_ptr,
                                                         int n, int e_total) {
  __shared__ int ws[4];
  int tid = threadIdx.x, lane = tid & 63, wid = tid >> 6;
  int id0 = blockIdx.x * 512 + tid * 2;
  int v0 = (id0 < n) ? cnt[id0] : 0;
  int v1 = (id0 + 1 < n) ? cnt[id0 + 1] : 0;
  int s = v0 + v1;
  int sc = s;
#pragma unroll
  for (int d = 1; d < 64; d <<= 1) {
    int t = __shfl_up(sc, d, 64);
    if (lane >= d) sc += t;
  }
  if (lane == 63) ws[wid] = sc;
  __syncthreads();
  int woff = 0;
  for (int w2 = 0; w2 < wid; ++w2) woff += ws[w2];
  int off = bsum[blockIdx.x] + woff + (sc - s);
  if (id0 < n) row_ptr[id0] = off;
  if (id0 + 1 < n) row_ptr[id0 + 1] = off + v0;
  if (blockIdx.x == 0 && tid == 0) row_ptr[n] = e_total;
}

// Fill adj: rank via LDS packed atomic; position = row_ptr[d] + chunk-prefix + rank.
__global__ __launch_bounds__(256) void fillx_kernel(const int* __restrict__ src,
                                                    const int* __restrict__ dst,
                                                    const unsigned int* __restrict__ hdst,
                                                    const int* __restrict__ row_ptr,
                                                    int* __restrict__ adj,
                                                    int e, int n, int ec) {
  __shared__ unsigned int h[32768];
  int c = blockIdx.x;
  int nw = (n + 1) >> 1;
  for (int w = threadIdx.x; w < nw; w += 256) h[w] = 0u;
  __syncthreads();
  int lo = c * ec;
  int hi = lo + ec; if (hi > e) hi = e;
  for (int i = lo + threadIdx.x; i < hi; i += 256) {
    int s = src[i];
    int d = dst[i];
    unsigned int old = atomicAdd(&h[d >> 1], (d & 1) ? 0x10000u : 1u);
    unsigned int rank = (d & 1) ? (old >> 16) : (old & 0xFFFFu);
    unsigned int pre = hdst[(size_t)c * nw + (d >> 1)];
    pre = (d & 1) ? (pre >> 16) : (pre & 0xFFFFu);
    adj[row_ptr[d] + (int)pre + (int)rank] = s;
  }
}

// g[i,:] = bf16(feat[i,:] * norm_src[i]); row n of BOTH buffers = zeros.
__global__ __launch_bounds__(256) void prescale_kernel(const float* __restrict__ feat,
                                                       const float* __restrict__ ns,
                                                       unsigned short* __restrict__ ga,
                                                       unsigned short* __restrict__ gb,
                                                       int n) {
  int i = blockIdx.x * 256 + threadIdx.x;  // uint2 (8-bf16) index
  if (i >= (n + 1) * 32) return;
  if (i >= n * 32) {  // zero row
    ((uint2*)ga)[i] = make_uint2(0u, 0u);
    ((uint2*)gb)[i] = make_uint2(0u, 0u);
    return;
  }
  float4 v = ((const float4*)feat)[i];
  float s = ns[i >> 5];
  unsigned int p0 = rtn16(v.x * s), p1 = rtn16(v.y * s);
  unsigned int p2 = rtn16(v.z * s), p3 = rtn16(v.w * s);
  ((uint2*)ga)[i] = make_uint2(p0 | (p1 << 16), p2 | (p3 << 16));
}

// ---------------- fused layer: agg (bf16 gather-sum) + f32 gemm + relu -------
// Pair-interleaved gather: each wave owns 8 rows processed as 4 PAIRS.
// Per pair, ALL adj indices + ALL 16 row-loads (2 uniform 16-edge blocks per
// node, zero-row pad for slots past degree; covers deg<=32, rare tail loop
// beyond) are issued before any accumulation -> 16 gather instrs in flight.
__global__ __launch_bounds__(256, 4) void layer_kernel(
    const unsigned short* __restrict__ gin, unsigned short* __restrict__ goutb,
    float* __restrict__ goutf, const int* __restrict__ adj,
    const int* __restrict__ row_ptr, const float* __restrict__ ns,
    const float* __restrict__ ndv, const float* __restrict__ W,
    const float* __restrict__ bias, int n, int last) {
  __shared__ float Xs[32][DD];
  int tid = threadIdx.x;
  int lane = tid & 63;
  int wv = tid >> 6;
  int m4 = lane & 15;   // 16B chunk of the 256B row
  int q = lane >> 4;    // quarter: edge slot within group of 4
  int row0 = blockIdx.x * 32;
  const uint4* g4 = (const uint4*)gin;

#define ACC8(a, v)                                   \
  a[0] += UNPK_LO(v.x); a[1] += UNPK_HI(v.x);        \
  a[2] += UNPK_LO(v.y); a[3] += UNPK_HI(v.y);        \
  a[4] += UNPK_LO(v.z); a[5] += UNPK_HI(v.z);        \
  a[6] += UNPK_LO(v.w); a[7] += UNPK_HI(v.w);

  for (int p = 0; p < 4; ++p) {
    int rA = wv + p * 8;
    int rB = rA + 4;
    int nodeA = row0 + rA, nodeB = row0 + rB;
    int begA = 0, endA = 0, begB = 0, endB = 0;
    float scA = 0.f, scB = 0.f;
    if (nodeA < n) { begA = row_ptr[nodeA]; endA = row_ptr[nodeA + 1]; scA = ndv[nodeA]; }
    if (nodeB < n) { begB = row_ptr[nodeB]; endB = row_ptr[nodeB + 1]; scB = ndv[nodeB]; }
    // indices for 2 blocks x 2 nodes (zero-row pad past degree)
    int eA[8], eB[8];
#pragma unroll
    for (int k = 0; k < 8; ++k) {
      int iA = begA + 4 * k + q;
      eA[k] = (iA < endA) ? adj[iA] : n;
    }
#pragma unroll
    for (int k = 0; k < 8; ++k) {
      int iB = begB + 4 * k + q;
      eB[k] = (iB < endB) ? adj[iB] : n;
    }
    // 16 independent row-loads in flight
    uint4 vA[8], vB[8];
#pragma unroll
    for (int k = 0; k < 8; ++k) vA[k] = g4[(size_t)eA[k] * 16 + m4];
#pragma unroll
    for (int k = 0; k < 8; ++k) vB[k] = g4[(size_t)eB[k] * 16 + m4];
    float aA[8] = {}, aB[8] = {};
#pragma unroll
    for (int k = 0; k < 8; ++k) { ACC8(aA, vA[k]); }
#pragma unroll
    for (int k = 0; k < 8; ++k) { ACC8(aB, vB[k]); }
    // rare tails (deg > 32)
    for (int j = begA + 32; j < endA; j += 16) {
      int i0 = j + q, i1 = j + 4 + q, i2 = j + 8 + q, i3 = j + 12 + q;
      int e0 = (i0 < endA) ? adj[i0] : n;
      int e1 = (i1 < endA) ? adj[i1] : n;
      int e2 = (i2 < endA) ? adj[i2] : n;
      int e3 = (i3 < endA) ? adj[i3] : n;
      uint4 t0 = g4[(size_t)e0 * 16 + m4];
      uint4 t1 = g4[(size_t)e1 * 16 + m4];
      uint4 t2 = g4[(size_t)e2 * 16 + m4];
      uint4 t3 = g4[(size_t)e3 * 16 + m4];
      ACC8(aA, t0); ACC8(aA, t1); ACC8(aA, t2); ACC8(aA, t3);
    }
    for (int j = begB + 32; j < endB; j += 16) {
      int i0 = j + q, i1 = j + 4 + q, i2 = j + 8 + q, i3 = j + 12 + q;
      int e0 = (i0 < endB) ? adj[i0] : n;
      int e1 = (i1 < endB) ? adj[i1] : n;
      int e2 = (i2 < endB) ? adj[i2] : n;
      int e3 = (i3 < endB) ? adj[i3] : n;
      uint4 t0 = g4[(size_t)e0 * 16 + m4];
      uint4 t1 = g4[(size_t)e1 * 16 + m4];
      uint4 t2 = g4[(size_t)e2 * 16 + m4];
      uint4 t3 = g4[(size_t)e3 * 16 + m4];
      ACC8(aB, t0); ACC8(aB, t1); ACC8(aB, t2); ACC8(aB, t3);
    }
    // reduce quarters: lanes {m4, m4+16, m4+32, m4+48}
#pragma unroll
    for (int k = 0; k < 8; ++k) {
      aA[k] += __shfl_xor(aA[k], 16, 64);
      aA[k] += __shfl_xor(aA[k], 32, 64);
      aB[k] += __shfl_xor(aB[k], 16, 64);
      aB[k] += __shfl_xor(aB[k], 32, 64);
    }
    if (q == 0) {
      float* xp = &Xs[rA][m4 * 8];
      xp[0] = aA[0] * scA; xp[1] = aA[1] * scA;
      xp[2] = aA[2] * scA; xp[3] = aA[3] * scA;
      xp[4] = aA[4] * scA; xp[5] = aA[5] * scA;
      xp[6] = aA[6] * scA; xp[7] = aA[7] * scA;
      float* yp = &Xs[rB][m4 * 8];
      yp[0] = aB[0] * scB; yp[1] = aB[1] * scB;
      yp[2] = aB[2] * scB; yp[3] = aB[3] * scB;
      yp[4] = aB[4] * scB; yp[5] = aB[5] * scB;
      yp[6] = aB[6] * scB; yp[7] = aB[7] * scB;
    }
  }
#undef ACC8
  __syncthreads();

  int tx = tid & 31;   // col group: cols tx*4..tx*4+3
  int ty = tid >> 5;   // row group: rows ty*4..ty*4+3
  float acc[4][4] = {};
  const float4* wp0 = (const float4*)W + tx;
  for (int k4 = 0; k4 < DD / 4; ++k4) {
    const float4* wp = wp0 + (size_t)k4 * 4 * 32;
    float4 w0 = wp[0];
    float4 w1 = wp[32];
    float4 w2 = wp[64];
    float4 w3 = wp[96];
#pragma unroll
    for (int i = 0; i < 4; ++i) {
      float4 x = *(const float4*)&Xs[ty * 4 + i][k4 * 4];
      acc[i][0] = fmaf(x.x, w0.x, acc[i][0]);
      acc[i][1] = fmaf(x.x, w0.y, acc[i][1]);
      acc[i][2] = fmaf(x.x, w0.z, acc[i][2]);
      acc[i][3] = fmaf(x.x, w0.w, acc[i][3]);
      acc[i][0] = fmaf(x.y, w1.x, acc[i][0]);
      acc[i][1] = fmaf(x.y, w1.y, acc[i][1]);
      acc[i][2] = fmaf(x.y, w1.z, acc[i][2]);
      acc[i][3] = fmaf(x.y, w1.w, acc[i][3]);
      acc[i][0] = fmaf(x.z, w2.x, acc[i][0]);
      acc[i][1] = fmaf(x.z, w2.y, acc[i][1]);
      acc[i][2] = fmaf(x.z, w2.z, acc[i][2]);
      acc[i][3] = fmaf(x.z, w2.w, acc[i][3]);
      acc[i][0] = fmaf(x.w, w3.x, acc[i][0]);
      acc[i][1] = fmaf(x.w, w3.y, acc[i][1]);
      acc[i][2] = fmaf(x.w, w3.z, acc[i][2]);
      acc[i][3] = fmaf(x.w, w3.w, acc[i][3]);
    }
  }
  float4 bv = *(const float4*)(bias + tx * 4);
#pragma unroll
  for (int i = 0; i < 4; ++i) {
    int r = row0 + ty * 4 + i;
    if (r < n) {
      float4 o;
      o.x = fmaxf(acc[i][0] + bv.x, 0.f);
      o.y = fmaxf(acc[i][1] + bv.y, 0.f);
      o.z = fmaxf(acc[i][2] + bv.z, 0.f);
      o.w = fmaxf(acc[i][3] + bv.w, 0.f);
      if (last) {
        *(float4*)(goutf + (size_t)r * DD + tx * 4) = o;
      } else {
        float s = ns[r];
        unsigned int p0 = rtn16(o.x * s), p1 = rtn16(o.y * s);
        unsigned int p2 = rtn16(o.z * s), p3 = rtn16(o.w * s);
        ((uint2*)(goutb + (size_t)r * DD))[tx] =
            make_uint2(p0 | (p1 << 16), p2 | (p3 << 16));
      }
    }
  }
}

// ---------------- launch ----------------

extern "C" void kernel_launch(void* const* d_in, const int* in_sizes, int n_in,
                              void* d_out, int out_size, void* d_ws, size_t ws_size,
                              hipStream_t stream) {
  const float* feat = (const float*)d_in[0];
  const int* src = (const int*)d_in[1];
  const int* dst = (const int*)d_in[2];
  const float* W = (const float*)d_in[3];
  const float* b = (const float*)d_in[4];
  const int N = in_sizes[0] / DD;
  const int E = in_sizes[1];
  const int L = in_sizes[3] / (DD * DD);
  const int NW = (N + 1) >> 1;
  const int EC = (E + NBC - 1) / NBC;

  char* p = (char*)d_ws;
  auto alloc = [&](size_t bytes) {
    void* r = (void*)p;
    p += (bytes + 255) & ~(size_t)255;
    return r;
  };
  int* deg_in = (int*)alloc((size_t)N * 4);
  int* row_ptr = (int*)alloc(((size_t)N + 1) * 4);
  int* adj = (int*)alloc((size_t)E * 4);
  float* norm_src = (float*)alloc((size_t)N * 4);
  float* norm_dst = (float*)alloc((size_t)N * 4);
  int* bsum = (int*)alloc(((size_t)N / 512 + 2) * 4);
  unsigned int* hsrc = (unsigned int*)alloc((size_t)NBC * NW * 4);
  unsigned int* hdst = (unsigned int*)alloc((size_t)NBC * NW * 4);
  unsigned short* ga = (unsigned short*)alloc(((size_t)N + 1) * DD * 2);
  unsigned short* gb = (unsigned short*)alloc(((size_t)N + 1) * DD * 2);

  const int nwb = (NW + 255) / 256;  // == ceil(N/512): shared by degnorm & scan

  hist2_kernel<<<2 * NBC, 256, 0, stream>>>(src, dst, hsrc, hdst, E, N, EC);
  degnorm_prefix_kernel<<<nwb, 256, 0, stream>>>(hsrc, hdst, deg_in, norm_src,
                                                 norm_dst, bsum, N);
  scan_bsum_kernel<<<1, 64, 0, stream>>>(bsum, nwb);
  scan_final_kernel<<<nwb, 256, 0, stream>>>(deg_in, bsum, row_ptr, N, E);
  fillx_kernel<<<NBC, 256, 0, stream>>>(src, dst, hdst, row_ptr, adj, E, N, EC);

  float* out_f = (float*)d_out;
  prescale_kernel<<<((N + 1) * 32 + 255) / 256, 256, 0, stream>>>(feat, norm_src,
                                                                  ga, gb, N);
  for (int l = 0; l < L; ++l) {
    const unsigned short* gi = (l & 1) ? gb : ga;
    unsigned short* go = (l & 1) ? ga : gb;
    int last = (l == L - 1) ? 1 : 0;
    layer_kernel<<<(N + 31) / 32, 256, 0, stream>>>(
        gi, go, out_f, adj, row_ptr, norm_src, norm_dst,
        W + (size_t)l * DD * DD, b + (size_t)l * DD, N, last);
  }
}